// Round 7
// baseline (704.147 us; speedup 1.0000x reference)
//
#include <hip/hip_runtime.h>

// ---------------------------------------------------------------------------
// GCN 3-layer forward.  N=50000, E=800000, D=H=128, C=40.
// Round 7: round-6 XCD-sliced aggregation with the R6 editing-artifact bug
// fixed (a3.z was clobbered by a stray fmaf line in the unrolled body).
// Slice = blockIdx % 8 rides round-robin workgroup->XCD dispatch; each XCD's
// gather working set = 50000 x 64 B = 3.2 MB (L2-resident); csr re-read per
// slice (8 x 6.4 MB streamed).  Per-(dst,feature) accumulation order
// identical to R5.
// ws layout: [deg:N int][rowptr:N+1 int][cursor:N int][dinv:N f32][bsum:1024 int]
//            [csr:E int2 (src, w-bits)][bufA:N*128 f32][bufB:N*128 f32]
// ---------------------------------------------------------------------------

__global__ void k_deg_count(const int* __restrict__ ei, int* __restrict__ deg, int E) {
    int e = blockIdx.x * blockDim.x + threadIdx.x;
    if (e < E) atomicAdd(&deg[ei[E + e]], 1);   // dst = ei[E+e]
}

__global__ void k_bsum(const int* __restrict__ deg, int* __restrict__ bsum, int n) {
    __shared__ int s[256];
    int t = threadIdx.x;
    int i = blockIdx.x * 256 + t;
    s[t] = (i < n) ? deg[i] : 0;
    __syncthreads();
    for (int off = 128; off > 0; off >>= 1) {
        if (t < off) s[t] += s[t + off];
        __syncthreads();
    }
    if (t == 0) bsum[blockIdx.x] = s[0];
}

__global__ void k_bscan(int* __restrict__ bsum, int* __restrict__ tot, int nb) {
    __shared__ int s[1024];
    int t = threadIdx.x;
    int v = (t < nb) ? bsum[t] : 0;
    s[t] = v;
    __syncthreads();
    for (int off = 1; off < 1024; off <<= 1) {
        int u = (t >= off) ? s[t - off] : 0;
        __syncthreads();
        s[t] += u;
        __syncthreads();
    }
    if (t < nb) bsum[t] = s[t] - v;
    if (t == nb - 1) tot[0] = s[t];
}

__global__ void k_rowptr(const int* __restrict__ deg, const int* __restrict__ bsum,
                         int* __restrict__ rowptr, int* __restrict__ cursor,
                         float* __restrict__ dinv, int n) {
    __shared__ int s[256];
    int t = threadIdx.x;
    int i = blockIdx.x * 256 + t;
    int v = (i < n) ? deg[i] : 0;
    s[t] = v;
    __syncthreads();
    for (int off = 1; off < 256; off <<= 1) {
        int u = (t >= off) ? s[t - off] : 0;
        __syncthreads();
        s[t] += u;
        __syncthreads();
    }
    if (i < n) {
        int ex = bsum[blockIdx.x] + s[t] - v;
        rowptr[i] = ex;
        cursor[i] = ex;
        dinv[i] = rsqrtf((float)(v + 1));   // +1 self-loop
    }
}

__global__ void k_fill(const int* __restrict__ ei, int* __restrict__ cursor,
                       const float* __restrict__ dinv, int2* __restrict__ csr, int E) {
    int e = blockIdx.x * blockDim.x + threadIdx.x;
    if (e >= E) return;
    int s = ei[e];
    int d = ei[E + e];
    int pos = atomicAdd(&cursor[d], 1);
    int2 p;
    p.x = s;
    p.y = __float_as_int(dinv[s] * dinv[d]);
    csr[pos] = p;
}

// ---- Y[N,128] = X[N,128] @ W[128,128].  BM=64, BK=32; 4x8 microtile. ----
__global__ __launch_bounds__(256) void k_gemm128(const float* __restrict__ X,
                                                 const float* __restrict__ W,
                                                 float* __restrict__ Y, int N) {
    __shared__ float sX[32][68];
    __shared__ float sW[32][128];
    const int tid = threadIdx.x;
    const int bm = blockIdx.x * 64;
    const int m0 = (tid >> 4) * 4;
    const int n0 = (tid & 15) * 8;
    const int xr = tid >> 3;
    const int xf = tid & 7;
    float acc[4][8] = {};
    for (int k0 = 0; k0 < 128; k0 += 32) {
        #pragma unroll
        for (int rr = 0; rr < 2; ++rr) {
            int row = bm + xr + rr * 32;
            int rc = min(row, N - 1);
            float4 v = *(const float4*)(X + (size_t)rc * 128 + k0 + xf * 4);
            int m = xr + rr * 32;
            sX[xf * 4 + 0][m] = v.x;
            sX[xf * 4 + 1][m] = v.y;
            sX[xf * 4 + 2][m] = v.z;
            sX[xf * 4 + 3][m] = v.w;
        }
        #pragma unroll
        for (int it = 0; it < 4; ++it) {
            int i = tid + it * 256;
            int wr = i >> 5;
            int wf = i & 31;
            *(float4*)(&sW[wr][wf * 4]) =
                *(const float4*)(W + (size_t)(k0 + wr) * 128 + wf * 4);
        }
        __syncthreads();
        #pragma unroll
        for (int kk = 0; kk < 32; ++kk) {
            float4 a  = *(const float4*)(&sX[kk][m0]);
            float4 b0 = *(const float4*)(&sW[kk][n0]);
            float4 b1 = *(const float4*)(&sW[kk][n0 + 4]);
            float av[4] = {a.x, a.y, a.z, a.w};
            float bv[8] = {b0.x, b0.y, b0.z, b0.w, b1.x, b1.y, b1.z, b1.w};
            #pragma unroll
            for (int r = 0; r < 4; ++r)
                #pragma unroll
                for (int c = 0; c < 8; ++c)
                    acc[r][c] = fmaf(av[r], bv[c], acc[r][c]);
        }
        __syncthreads();
    }
    #pragma unroll
    for (int r = 0; r < 4; ++r) {
        int row = bm + m0 + r;
        if (row < N) {
            float4 o0 = {acc[r][0], acc[r][1], acc[r][2], acc[r][3]};
            float4 o1 = {acc[r][4], acc[r][5], acc[r][6], acc[r][7]};
            *(float4*)(Y + (size_t)row * 128 + n0)     = o0;
            *(float4*)(Y + (size_t)row * 128 + n0 + 4) = o1;
        }
    }
}

// ---- Y[N,40] = X[N,128] @ W[128,40].  BM=128, BK=32; 4x5 microtile. ----
__global__ __launch_bounds__(256) void k_gemm40(const float* __restrict__ X,
                                                const float* __restrict__ W,
                                                float* __restrict__ Y, int N) {
    __shared__ float sX[32][132];
    __shared__ float sW[32][40];
    const int tid = threadIdx.x;
    const int bm = blockIdx.x * 128;
    const int m0 = (tid >> 3) * 4;
    const int n0 = (tid & 7) * 5;
    const int xf = tid & 7;
    float acc[4][5] = {};
    for (int k0 = 0; k0 < 128; k0 += 32) {
        #pragma unroll
        for (int it = 0; it < 4; ++it) {
            int i = tid + it * 256;
            int row = bm + (i >> 3);
            int rc = min(row, N - 1);
            float4 v = *(const float4*)(X + (size_t)rc * 128 + k0 + xf * 4);
            int m = i >> 3;
            sX[xf * 4 + 0][m] = v.x;
            sX[xf * 4 + 1][m] = v.y;
            sX[xf * 4 + 2][m] = v.z;
            sX[xf * 4 + 3][m] = v.w;
        }
        for (int i = tid; i < 320; i += 256) {
            int wr = i / 10;
            int wf = i - wr * 10;
            *(float4*)(&sW[wr][wf * 4]) =
                *(const float4*)(W + (size_t)(k0 + wr) * 40 + wf * 4);
        }
        __syncthreads();
        #pragma unroll
        for (int kk = 0; kk < 32; ++kk) {
            float4 a = *(const float4*)(&sX[kk][m0]);
            float av[4] = {a.x, a.y, a.z, a.w};
            #pragma unroll
            for (int c = 0; c < 5; ++c) {
                float b = sW[kk][n0 + c];
                #pragma unroll
                for (int r = 0; r < 4; ++r)
                    acc[r][c] = fmaf(av[r], b, acc[r][c]);
            }
        }
        __syncthreads();
    }
    #pragma unroll
    for (int r = 0; r < 4; ++r) {
        int row = bm + m0 + r;
        if (row < N) {
            #pragma unroll
            for (int c = 0; c < 5; ++c)
                Y[(size_t)row * 40 + n0 + c] = acc[r][c];
        }
    }
}

// XCD-sliced aggregation, F=128.  slice = blockIdx % 8; one thread owns
// (dst, 16-feature slice) = one 64-B line of each gathered row.
template <bool RELU>
__global__ __launch_bounds__(256) void k_agg128s(
        const float* __restrict__ XW, const int* __restrict__ rowptr,
        const int2* __restrict__ csr, const float* __restrict__ dinv,
        const float* __restrict__ bias, float* __restrict__ out, int n) {
    const int slice = blockIdx.x & 7;
    const int d = (blockIdx.x >> 3) * 256 + threadIdx.x;
    if (d >= n) return;
    const float* __restrict__ base = XW + slice * 16;
    float dv = dinv[d];
    float w = dv * dv;
    const float* xr = base + (size_t)d * 128;
    float4 a0 = *(const float4*)(xr + 0);
    float4 a1 = *(const float4*)(xr + 4);
    float4 a2 = *(const float4*)(xr + 8);
    float4 a3 = *(const float4*)(xr + 12);
    a0.x *= w; a0.y *= w; a0.z *= w; a0.w *= w;
    a1.x *= w; a1.y *= w; a1.z *= w; a1.w *= w;
    a2.x *= w; a2.y *= w; a2.z *= w; a2.w *= w;
    a3.x *= w; a3.y *= w; a3.z *= w; a3.w *= w;
    int j = rowptr[d], end = rowptr[d + 1];
    for (; j + 2 <= end; j += 2) {
        int2 p0 = csr[j], p1 = csr[j + 1];
        float w0 = __int_as_float(p0.y);
        float w1 = __int_as_float(p1.y);
        const float* r0 = base + (size_t)p0.x * 128;
        const float* r1 = base + (size_t)p1.x * 128;
        float4 u0 = *(const float4*)(r0 + 0);
        float4 u1 = *(const float4*)(r0 + 4);
        float4 u2 = *(const float4*)(r0 + 8);
        float4 u3 = *(const float4*)(r0 + 12);
        float4 v0 = *(const float4*)(r1 + 0);
        float4 v1 = *(const float4*)(r1 + 4);
        float4 v2 = *(const float4*)(r1 + 8);
        float4 v3 = *(const float4*)(r1 + 12);
        a0.x = fmaf(w0, u0.x, a0.x); a0.y = fmaf(w0, u0.y, a0.y);
        a0.z = fmaf(w0, u0.z, a0.z); a0.w = fmaf(w0, u0.w, a0.w);
        a1.x = fmaf(w0, u1.x, a1.x); a1.y = fmaf(w0, u1.y, a1.y);
        a1.z = fmaf(w0, u1.z, a1.z); a1.w = fmaf(w0, u1.w, a1.w);
        a2.x = fmaf(w0, u2.x, a2.x); a2.y = fmaf(w0, u2.y, a2.y);
        a2.z = fmaf(w0, u2.z, a2.z); a2.w = fmaf(w0, u2.w, a2.w);
        a3.x = fmaf(w0, u3.x, a3.x); a3.y = fmaf(w0, u3.y, a3.y);
        a3.z = fmaf(w0, u3.z, a3.z); a3.w = fmaf(w0, u3.w, a3.w);
        a0.x = fmaf(w1, v0.x, a0.x); a0.y = fmaf(w1, v0.y, a0.y);
        a0.z = fmaf(w1, v0.z, a0.z); a0.w = fmaf(w1, v0.w, a0.w);
        a1.x = fmaf(w1, v1.x, a1.x); a1.y = fmaf(w1, v1.y, a1.y);
        a1.z = fmaf(w1, v1.z, a1.z); a1.w = fmaf(w1, v1.w, a1.w);
        a2.x = fmaf(w1, v2.x, a2.x); a2.y = fmaf(w1, v2.y, a2.y);
        a2.z = fmaf(w1, v2.z, a2.z); a2.w = fmaf(w1, v2.w, a2.w);
        a3.x = fmaf(w1, v3.x, a3.x); a3.y = fmaf(w1, v3.y, a3.y);
        a3.z = fmaf(w1, v3.z, a3.z); a3.w = fmaf(w1, v3.w, a3.w);
    }
    for (; j < end; ++j) {
        int2 p = csr[j];
        float wj = __int_as_float(p.y);
        const float* r0 = base + (size_t)p.x * 128;
        float4 u0 = *(const float4*)(r0 + 0);
        float4 u1 = *(const float4*)(r0 + 4);
        float4 u2 = *(const float4*)(r0 + 8);
        float4 u3 = *(const float4*)(r0 + 12);
        a0.x = fmaf(wj, u0.x, a0.x); a0.y = fmaf(wj, u0.y, a0.y);
        a0.z = fmaf(wj, u0.z, a0.z); a0.w = fmaf(wj, u0.w, a0.w);
        a1.x = fmaf(wj, u1.x, a1.x); a1.y = fmaf(wj, u1.y, a1.y);
        a1.z = fmaf(wj, u1.z, a1.z); a1.w = fmaf(wj, u1.w, a1.w);
        a2.x = fmaf(wj, u2.x, a2.x); a2.y = fmaf(wj, u2.y, a2.y);
        a2.z = fmaf(wj, u2.z, a2.z); a2.w = fmaf(wj, u2.w, a2.w);
        a3.x = fmaf(wj, u3.x, a3.x); a3.y = fmaf(wj, u3.y, a3.y);
        a3.z = fmaf(wj, u3.z, a3.z); a3.w = fmaf(wj, u3.w, a3.w);
    }
    const float* bb = bias + slice * 16;
    float4 b0 = *(const float4*)(bb + 0);
    float4 b1 = *(const float4*)(bb + 4);
    float4 b2 = *(const float4*)(bb + 8);
    float4 b3 = *(const float4*)(bb + 12);
    a0.x += b0.x; a0.y += b0.y; a0.z += b0.z; a0.w += b0.w;
    a1.x += b1.x; a1.y += b1.y; a1.z += b1.z; a1.w += b1.w;
    a2.x += b2.x; a2.y += b2.y; a2.z += b2.z; a2.w += b2.w;
    a3.x += b3.x; a3.y += b3.y; a3.z += b3.z; a3.w += b3.w;
    if (RELU) {
        a0.x = fmaxf(a0.x, 0.f); a0.y = fmaxf(a0.y, 0.f);
        a0.z = fmaxf(a0.z, 0.f); a0.w = fmaxf(a0.w, 0.f);
        a1.x = fmaxf(a1.x, 0.f); a1.y = fmaxf(a1.y, 0.f);
        a1.z = fmaxf(a1.z, 0.f); a1.w = fmaxf(a1.w, 0.f);
        a2.x = fmaxf(a2.x, 0.f); a2.y = fmaxf(a2.y, 0.f);
        a2.z = fmaxf(a2.z, 0.f); a2.w = fmaxf(a2.w, 0.f);
        a3.x = fmaxf(a3.x, 0.f); a3.y = fmaxf(a3.y, 0.f);
        a3.z = fmaxf(a3.z, 0.f); a3.w = fmaxf(a3.w, 0.f);
    }
    float* o = out + (size_t)d * 128 + slice * 16;
    *(float4*)(o + 0)  = a0;
    *(float4*)(o + 4)  = a1;
    *(float4*)(o + 8)  = a2;
    *(float4*)(o + 12) = a3;
}

__global__ void k_agg40(const float* __restrict__ XW, const int* __restrict__ rowptr,
                        const int2* __restrict__ csr, const float* __restrict__ dinv,
                        const float* __restrict__ bias, float* __restrict__ out, int n) {
    int wave = threadIdx.x >> 6;
    int lane = threadIdx.x & 63;
    int d = blockIdx.x * 4 + wave;
    if (d >= n || lane >= 40) return;
    float dv = dinv[d];
    float acc = dv * dv * XW[(size_t)d * 40 + lane];
    int beg = rowptr[d], end = rowptr[d + 1];
    int j = beg;
    for (; j + 4 <= end; j += 4) {
        int2 p0 = csr[j + 0], p1 = csr[j + 1], p2 = csr[j + 2], p3 = csr[j + 3];
        float u0 = XW[(size_t)p0.x * 40 + lane];
        float u1 = XW[(size_t)p1.x * 40 + lane];
        float u2 = XW[(size_t)p2.x * 40 + lane];
        float u3 = XW[(size_t)p3.x * 40 + lane];
        acc = fmaf(__int_as_float(p0.y), u0, acc);
        acc = fmaf(__int_as_float(p1.y), u1, acc);
        acc = fmaf(__int_as_float(p2.y), u2, acc);
        acc = fmaf(__int_as_float(p3.y), u3, acc);
    }
    for (; j < end; ++j) {
        int2 p = csr[j];
        acc = fmaf(__int_as_float(p.y), XW[(size_t)p.x * 40 + lane], acc);
    }
    out[(size_t)d * 40 + lane] = acc + bias[lane];
}

static inline int cdiv(long long a, int b) { return (int)((a + b - 1) / b); }

extern "C" void kernel_launch(void* const* d_in, const int* in_sizes, int n_in,
                              void* d_out, int out_size, void* d_ws, size_t ws_size,
                              hipStream_t stream) {
    const float* x  = (const float*)d_in[0];
    const int*   ei = (const int*)d_in[1];
    const float* W1 = (const float*)d_in[2];
    const float* b1 = (const float*)d_in[3];
    const float* W2 = (const float*)d_in[4];
    const float* b2 = (const float*)d_in[5];
    const float* W3 = (const float*)d_in[6];
    const float* b3 = (const float*)d_in[7];
    float* out = (float*)d_out;

    const int N = in_sizes[0] / 128;   // 50000
    const int E = in_sizes[1] / 2;     // 800000

    char* ws = (char*)d_ws;
    int*   deg    = (int*)ws;                 ws += (size_t)N * 4;
    int*   rowptr = (int*)ws;                 ws += (size_t)(N + 1) * 4;
    int*   cursor = (int*)ws;                 ws += (size_t)N * 4;
    float* dinv   = (float*)ws;               ws += (size_t)N * 4;
    int*   bsum   = (int*)ws;                 ws += (size_t)1024 * 4;
    ws = (char*)(((uintptr_t)ws + 15) & ~(uintptr_t)15);
    int2*  csr    = (int2*)ws;                ws += (size_t)E * 8;
    float* bufA   = (float*)ws;               ws += (size_t)N * 128 * 4;
    float* bufB   = (float*)ws;

    const int BT = 256;
    const int nb = cdiv(N, 256);
    const int aggGrid = nb * 8;   // dst-tiles x 8 feature slices

    // CSR build (per call; no state survives between calls)
    hipMemsetAsync(deg, 0, (size_t)N * 4, stream);
    k_deg_count<<<cdiv(E, BT), BT, 0, stream>>>(ei, deg, E);
    k_bsum<<<nb, 256, 0, stream>>>(deg, bsum, N);
    k_bscan<<<1, 1024, 0, stream>>>(bsum, rowptr + N, nb);
    k_rowptr<<<nb, 256, 0, stream>>>(deg, bsum, rowptr, cursor, dinv, N);
    k_fill<<<cdiv(E, BT), BT, 0, stream>>>(ei, cursor, dinv, csr, E);

    // layer 1
    k_gemm128<<<cdiv(N, 64), 256, 0, stream>>>(x, W1, bufA, N);
    k_agg128s<true><<<aggGrid, 256, 0, stream>>>(bufA, rowptr, csr, dinv, b1, bufB, N);
    // layer 2
    k_gemm128<<<cdiv(N, 64), 256, 0, stream>>>(bufB, W2, bufA, N);
    k_agg128s<true><<<aggGrid, 256, 0, stream>>>(bufA, rowptr, csr, dinv, b2, bufB, N);
    // layer 3
    k_gemm40<<<cdiv(N, 128), 256, 0, stream>>>(bufB, W3, bufA, N);
    k_agg40<<<cdiv(N, 4), BT, 0, stream>>>(bufA, rowptr, csr, dinv, b3, out, N);
}

// Round 8
// 411.557 us; speedup vs baseline: 1.7109x; 1.7109x over previous
//
#include <hip/hip_runtime.h>

// ---------------------------------------------------------------------------
// GCN 3-layer forward.  N=50000, E=800000, D=H=128, C=40.
// Round 8: R7's 64-B/lane sliced gather was a 3x regression (620 MB fetch:
// lost wave coalescing + 128-B line amplification).  Revert to wave-
// cooperative row gather, upgraded to HALF-WAVE per dst (32 lanes x float4
// = 512 B row; 2 independent edge streams/wave, unroll 8 each -> 16 gathers
// in flight).  Also fix gemm128's 4-way sW bank conflict (3.8M cycles in R7
// profile): thread owns cols {4c..4c+3} u {64+4c..67+4c} -> stride-4 reads.
// Per-dst FMA order unchanged everywhere.
// ws layout: [deg:N int][rowptr:N+1 int][cursor:N int][dinv:N f32][bsum:1024 int]
//            [csr:E int2 (src, w-bits)][bufA:N*128 f32][bufB:N*128 f32]
// ---------------------------------------------------------------------------

__global__ void k_deg_count(const int* __restrict__ ei, int* __restrict__ deg, int E) {
    int e = blockIdx.x * blockDim.x + threadIdx.x;
    if (e < E) atomicAdd(&deg[ei[E + e]], 1);   // dst = ei[E+e]
}

__global__ void k_bsum(const int* __restrict__ deg, int* __restrict__ bsum, int n) {
    __shared__ int s[256];
    int t = threadIdx.x;
    int i = blockIdx.x * 256 + t;
    s[t] = (i < n) ? deg[i] : 0;
    __syncthreads();
    for (int off = 128; off > 0; off >>= 1) {
        if (t < off) s[t] += s[t + off];
        __syncthreads();
    }
    if (t == 0) bsum[blockIdx.x] = s[0];
}

__global__ void k_bscan(int* __restrict__ bsum, int* __restrict__ tot, int nb) {
    __shared__ int s[1024];
    int t = threadIdx.x;
    int v = (t < nb) ? bsum[t] : 0;
    s[t] = v;
    __syncthreads();
    for (int off = 1; off < 1024; off <<= 1) {
        int u = (t >= off) ? s[t - off] : 0;
        __syncthreads();
        s[t] += u;
        __syncthreads();
    }
    if (t < nb) bsum[t] = s[t] - v;
    if (t == nb - 1) tot[0] = s[t];
}

__global__ void k_rowptr(const int* __restrict__ deg, const int* __restrict__ bsum,
                         int* __restrict__ rowptr, int* __restrict__ cursor,
                         float* __restrict__ dinv, int n) {
    __shared__ int s[256];
    int t = threadIdx.x;
    int i = blockIdx.x * 256 + t;
    int v = (i < n) ? deg[i] : 0;
    s[t] = v;
    __syncthreads();
    for (int off = 1; off < 256; off <<= 1) {
        int u = (t >= off) ? s[t - off] : 0;
        __syncthreads();
        s[t] += u;
        __syncthreads();
    }
    if (i < n) {
        int ex = bsum[blockIdx.x] + s[t] - v;
        rowptr[i] = ex;
        cursor[i] = ex;
        dinv[i] = rsqrtf((float)(v + 1));   // +1 self-loop
    }
}

__global__ void k_fill(const int* __restrict__ ei, int* __restrict__ cursor,
                       const float* __restrict__ dinv, int2* __restrict__ csr, int E) {
    int e = blockIdx.x * blockDim.x + threadIdx.x;
    if (e >= E) return;
    int s = ei[e];
    int d = ei[E + e];
    int pos = atomicAdd(&cursor[d], 1);
    int2 p;
    p.x = s;
    p.y = __float_as_int(dinv[s] * dinv[d]);
    csr[pos] = p;
}

// ---- Y[N,128] = X[N,128] @ W[128,128].  BM=64, BK=32; 4x8 microtile.
// Column split {4c, 64+4c} keeps both sW ds_read_b128 at 2-way bank aliasing.
__global__ __launch_bounds__(256) void k_gemm128(const float* __restrict__ X,
                                                 const float* __restrict__ W,
                                                 float* __restrict__ Y, int N) {
    __shared__ float sX[32][68];
    __shared__ float sW[32][128];
    const int tid = threadIdx.x;
    const int bm = blockIdx.x * 64;
    const int m0 = (tid >> 4) * 4;   // 0..60
    const int c4 = (tid & 15) * 4;   // 0..60: cols c4..c4+3 and 64+c4..64+c4+3
    const int xr = tid >> 3;
    const int xf = tid & 7;
    float acc[4][8] = {};
    for (int k0 = 0; k0 < 128; k0 += 32) {
        #pragma unroll
        for (int rr = 0; rr < 2; ++rr) {
            int row = bm + xr + rr * 32;
            int rc = min(row, N - 1);
            float4 v = *(const float4*)(X + (size_t)rc * 128 + k0 + xf * 4);
            int m = xr + rr * 32;
            sX[xf * 4 + 0][m] = v.x;
            sX[xf * 4 + 1][m] = v.y;
            sX[xf * 4 + 2][m] = v.z;
            sX[xf * 4 + 3][m] = v.w;
        }
        #pragma unroll
        for (int it = 0; it < 4; ++it) {
            int i = tid + it * 256;
            int wr = i >> 5;
            int wf = i & 31;
            *(float4*)(&sW[wr][wf * 4]) =
                *(const float4*)(W + (size_t)(k0 + wr) * 128 + wf * 4);
        }
        __syncthreads();
        #pragma unroll
        for (int kk = 0; kk < 32; ++kk) {
            float4 a  = *(const float4*)(&sX[kk][m0]);
            float4 b0 = *(const float4*)(&sW[kk][c4]);
            float4 b1 = *(const float4*)(&sW[kk][64 + c4]);
            float av[4] = {a.x, a.y, a.z, a.w};
            float bv[8] = {b0.x, b0.y, b0.z, b0.w, b1.x, b1.y, b1.z, b1.w};
            #pragma unroll
            for (int r = 0; r < 4; ++r)
                #pragma unroll
                for (int c = 0; c < 8; ++c)
                    acc[r][c] = fmaf(av[r], bv[c], acc[r][c]);
        }
        __syncthreads();
    }
    #pragma unroll
    for (int r = 0; r < 4; ++r) {
        int row = bm + m0 + r;
        if (row < N) {
            float4 o0 = {acc[r][0], acc[r][1], acc[r][2], acc[r][3]};
            float4 o1 = {acc[r][4], acc[r][5], acc[r][6], acc[r][7]};
            *(float4*)(Y + (size_t)row * 128 + c4)      = o0;
            *(float4*)(Y + (size_t)row * 128 + 64 + c4) = o1;
        }
    }
}

// ---- Y[N,40] = X[N,128] @ W[128,40].  BM=128, BK=32; 4x5 microtile. ----
__global__ __launch_bounds__(256) void k_gemm40(const float* __restrict__ X,
                                                const float* __restrict__ W,
                                                float* __restrict__ Y, int N) {
    __shared__ float sX[32][132];
    __shared__ float sW[32][40];
    const int tid = threadIdx.x;
    const int bm = blockIdx.x * 128;
    const int m0 = (tid >> 3) * 4;
    const int n0 = (tid & 7) * 5;
    const int xf = tid & 7;
    float acc[4][5] = {};
    for (int k0 = 0; k0 < 128; k0 += 32) {
        #pragma unroll
        for (int it = 0; it < 4; ++it) {
            int i = tid + it * 256;
            int row = bm + (i >> 3);
            int rc = min(row, N - 1);
            float4 v = *(const float4*)(X + (size_t)rc * 128 + k0 + xf * 4);
            int m = i >> 3;
            sX[xf * 4 + 0][m] = v.x;
            sX[xf * 4 + 1][m] = v.y;
            sX[xf * 4 + 2][m] = v.z;
            sX[xf * 4 + 3][m] = v.w;
        }
        for (int i = tid; i < 320; i += 256) {
            int wr = i / 10;
            int wf = i - wr * 10;
            *(float4*)(&sW[wr][wf * 4]) =
                *(const float4*)(W + (size_t)(k0 + wr) * 40 + wf * 4);
        }
        __syncthreads();
        #pragma unroll
        for (int kk = 0; kk < 32; ++kk) {
            float4 a = *(const float4*)(&sX[kk][m0]);
            float av[4] = {a.x, a.y, a.z, a.w};
            #pragma unroll
            for (int c = 0; c < 5; ++c) {
                float b = sW[kk][n0 + c];
                #pragma unroll
                for (int r = 0; r < 4; ++r)
                    acc[r][c] = fmaf(av[r], b, acc[r][c]);
            }
        }
        __syncthreads();
    }
    #pragma unroll
    for (int r = 0; r < 4; ++r) {
        int row = bm + m0 + r;
        if (row < N) {
            #pragma unroll
            for (int c = 0; c < 5; ++c)
                Y[(size_t)row * 40 + n0 + c] = acc[r][c];
        }
    }
}

// Half-wave (32 lanes) per dst, F=128: lane holds float4 (4 cols); a half-wave
// gather reads one full 512-B row coalesced.  Two independent edge streams per
// wave; unroll 8 each -> up to 16 gathers in flight.  FMA order per dst
// identical to the reference sequential order.
template <bool RELU>
__global__ __launch_bounds__(256) void k_agg128(
        const float* __restrict__ XW, const int* __restrict__ rowptr,
        const int2* __restrict__ csr, const float* __restrict__ dinv,
        const float* __restrict__ bias, float* __restrict__ out, int n) {
    const int lane = threadIdx.x & 31;          // lane within half-wave
    const int sub  = threadIdx.x >> 5;          // 0..7: half-wave index in block
    const int d = blockIdx.x * 8 + sub;
    if (d >= n) return;
    const float4* xw4 = (const float4*)XW;      // row stride 32 float4
    float dv = dinv[d];
    float w = dv * dv;
    float4 a = xw4[(size_t)d * 32 + lane];
    a.x *= w; a.y *= w; a.z *= w; a.w *= w;
    int j = rowptr[d], end = rowptr[d + 1];
    for (; j + 8 <= end; j += 8) {
        int2 p0 = csr[j + 0], p1 = csr[j + 1], p2 = csr[j + 2], p3 = csr[j + 3];
        int2 p4 = csr[j + 4], p5 = csr[j + 5], p6 = csr[j + 6], p7 = csr[j + 7];
        float4 u0 = xw4[(size_t)p0.x * 32 + lane];
        float4 u1 = xw4[(size_t)p1.x * 32 + lane];
        float4 u2 = xw4[(size_t)p2.x * 32 + lane];
        float4 u3 = xw4[(size_t)p3.x * 32 + lane];
        float4 u4 = xw4[(size_t)p4.x * 32 + lane];
        float4 u5 = xw4[(size_t)p5.x * 32 + lane];
        float4 u6 = xw4[(size_t)p6.x * 32 + lane];
        float4 u7 = xw4[(size_t)p7.x * 32 + lane];
        float w0 = __int_as_float(p0.y), w1 = __int_as_float(p1.y);
        float w2 = __int_as_float(p2.y), w3 = __int_as_float(p3.y);
        float w4 = __int_as_float(p4.y), w5 = __int_as_float(p5.y);
        float w6 = __int_as_float(p6.y), w7 = __int_as_float(p7.y);
        a.x = fmaf(w0, u0.x, a.x); a.y = fmaf(w0, u0.y, a.y);
        a.z = fmaf(w0, u0.z, a.z); a.w = fmaf(w0, u0.w, a.w);
        a.x = fmaf(w1, u1.x, a.x); a.y = fmaf(w1, u1.y, a.y);
        a.z = fmaf(w1, u1.z, a.z); a.w = fmaf(w1, u1.w, a.w);
        a.x = fmaf(w2, u2.x, a.x); a.y = fmaf(w2, u2.y, a.y);
        a.z = fmaf(w2, u2.z, a.z); a.w = fmaf(w2, u2.w, a.w);
        a.x = fmaf(w3, u3.x, a.x); a.y = fmaf(w3, u3.y, a.y);
        a.z = fmaf(w3, u3.z, a.z); a.w = fmaf(w3, u3.w, a.w);
        a.x = fmaf(w4, u4.x, a.x); a.y = fmaf(w4, u4.y, a.y);
        a.z = fmaf(w4, u4.z, a.z); a.w = fmaf(w4, u4.w, a.w);
        a.x = fmaf(w5, u5.x, a.x); a.y = fmaf(w5, u5.y, a.y);
        a.z = fmaf(w5, u5.z, a.z); a.w = fmaf(w5, u5.w, a.w);
        a.x = fmaf(w6, u6.x, a.x); a.y = fmaf(w6, u6.y, a.y);
        a.z = fmaf(w6, u6.z, a.z); a.w = fmaf(w6, u6.w, a.w);
        a.x = fmaf(w7, u7.x, a.x); a.y = fmaf(w7, u7.y, a.y);
        a.z = fmaf(w7, u7.z, a.z); a.w = fmaf(w7, u7.w, a.w);
    }
    for (; j < end; ++j) {
        int2 p = csr[j];
        float wj = __int_as_float(p.y);
        float4 u = xw4[(size_t)p.x * 32 + lane];
        a.x = fmaf(wj, u.x, a.x); a.y = fmaf(wj, u.y, a.y);
        a.z = fmaf(wj, u.z, a.z); a.w = fmaf(wj, u.w, a.w);
    }
    float4 b = ((const float4*)bias)[lane];
    a.x += b.x; a.y += b.y; a.z += b.z; a.w += b.w;
    if (RELU) {
        a.x = fmaxf(a.x, 0.f); a.y = fmaxf(a.y, 0.f);
        a.z = fmaxf(a.z, 0.f); a.w = fmaxf(a.w, 0.f);
    }
    ((float4*)out)[(size_t)d * 32 + lane] = a;
}

__global__ void k_agg40(const float* __restrict__ XW, const int* __restrict__ rowptr,
                        const int2* __restrict__ csr, const float* __restrict__ dinv,
                        const float* __restrict__ bias, float* __restrict__ out, int n) {
    int wave = threadIdx.x >> 6;
    int lane = threadIdx.x & 63;
    int d = blockIdx.x * 4 + wave;
    if (d >= n || lane >= 40) return;
    float dv = dinv[d];
    float acc = dv * dv * XW[(size_t)d * 40 + lane];
    int beg = rowptr[d], end = rowptr[d + 1];
    int j = beg;
    for (; j + 4 <= end; j += 4) {
        int2 p0 = csr[j + 0], p1 = csr[j + 1], p2 = csr[j + 2], p3 = csr[j + 3];
        float u0 = XW[(size_t)p0.x * 40 + lane];
        float u1 = XW[(size_t)p1.x * 40 + lane];
        float u2 = XW[(size_t)p2.x * 40 + lane];
        float u3 = XW[(size_t)p3.x * 40 + lane];
        acc = fmaf(__int_as_float(p0.y), u0, acc);
        acc = fmaf(__int_as_float(p1.y), u1, acc);
        acc = fmaf(__int_as_float(p2.y), u2, acc);
        acc = fmaf(__int_as_float(p3.y), u3, acc);
    }
    for (; j < end; ++j) {
        int2 p = csr[j];
        acc = fmaf(__int_as_float(p.y), XW[(size_t)p.x * 40 + lane], acc);
    }
    out[(size_t)d * 40 + lane] = acc + bias[lane];
}

static inline int cdiv(long long a, int b) { return (int)((a + b - 1) / b); }

extern "C" void kernel_launch(void* const* d_in, const int* in_sizes, int n_in,
                              void* d_out, int out_size, void* d_ws, size_t ws_size,
                              hipStream_t stream) {
    const float* x  = (const float*)d_in[0];
    const int*   ei = (const int*)d_in[1];
    const float* W1 = (const float*)d_in[2];
    const float* b1 = (const float*)d_in[3];
    const float* W2 = (const float*)d_in[4];
    const float* b2 = (const float*)d_in[5];
    const float* W3 = (const float*)d_in[6];
    const float* b3 = (const float*)d_in[7];
    float* out = (float*)d_out;

    const int N = in_sizes[0] / 128;   // 50000
    const int E = in_sizes[1] / 2;     // 800000

    char* ws = (char*)d_ws;
    int*   deg    = (int*)ws;                 ws += (size_t)N * 4;
    int*   rowptr = (int*)ws;                 ws += (size_t)(N + 1) * 4;
    int*   cursor = (int*)ws;                 ws += (size_t)N * 4;
    float* dinv   = (float*)ws;               ws += (size_t)N * 4;
    int*   bsum   = (int*)ws;                 ws += (size_t)1024 * 4;
    ws = (char*)(((uintptr_t)ws + 15) & ~(uintptr_t)15);
    int2*  csr    = (int2*)ws;                ws += (size_t)E * 8;
    float* bufA   = (float*)ws;               ws += (size_t)N * 128 * 4;
    float* bufB   = (float*)ws;

    const int BT = 256;
    const int nb = cdiv(N, 256);

    // CSR build (per call; no state survives between calls)
    hipMemsetAsync(deg, 0, (size_t)N * 4, stream);
    k_deg_count<<<cdiv(E, BT), BT, 0, stream>>>(ei, deg, E);
    k_bsum<<<nb, 256, 0, stream>>>(deg, bsum, N);
    k_bscan<<<1, 1024, 0, stream>>>(bsum, rowptr + N, nb);
    k_rowptr<<<nb, 256, 0, stream>>>(deg, bsum, rowptr, cursor, dinv, N);
    k_fill<<<cdiv(E, BT), BT, 0, stream>>>(ei, cursor, dinv, csr, E);

    // layer 1
    k_gemm128<<<cdiv(N, 64), 256, 0, stream>>>(x, W1, bufA, N);
    k_agg128<true><<<cdiv(N, 8), 256, 0, stream>>>(bufA, rowptr, csr, dinv, b1, bufB, N);
    // layer 2
    k_gemm128<<<cdiv(N, 64), 256, 0, stream>>>(bufB, W2, bufA, N);
    k_agg128<true><<<cdiv(N, 8), 256, 0, stream>>>(bufA, rowptr, csr, dinv, b2, bufB, N);
    // layer 3
    k_gemm40<<<cdiv(N, 128), 256, 0, stream>>>(bufB, W3, bufA, N);
    k_agg40<<<cdiv(N, 4), BT, 0, stream>>>(bufA, rowptr, csr, dinv, b3, out, N);
}

// Round 9
// 367.644 us; speedup vs baseline: 1.9153x; 1.1194x over previous
//
#include <hip/hip_runtime.h>

typedef unsigned short ushort_t;
typedef unsigned int uint_t;

// ---------------------------------------------------------------------------
// GCN 3-layer forward.  N=50000, E=800000, D=H=128, C=40.
// Round 9: bf16 staging buffer for the F=128 gathers.  R8 showed the gather
// at a traffic ceiling (FETCH 226 MB pinned, 3.7 TB/s, MLP-insensitive) —
// so halve the bytes: gemm128 writes XW in bf16 (RNE), agg128 gathers
// ushort4 (256 B/row = 2 lines/edge) and accumulates in fp32.  Layer-3 path
// (gemm40/agg40) stays fp32; agg40 upgraded to half-wave/dst (float2 x 20
// lanes).  csr reads via nontemporal loads (don't evict gather lines).
// Error budget: bf16 round sigma ~6.5e-4/elem, aggregation contracts by
// sqrt(sum w^2)~0.24, W2/W3 contract further -> ~+2e-4 final absmax.
// ws layout: [deg:N int][rowptr:N+1 int][cursor:N int][dinv:N f32][bsum:1024 int]
//            [csr:E int2 (src, w-bits)][bufA:N*128 f32-sized][bufB:N*128 f32]
// ---------------------------------------------------------------------------

__global__ void k_deg_count(const int* __restrict__ ei, int* __restrict__ deg, int E) {
    int e = blockIdx.x * blockDim.x + threadIdx.x;
    if (e < E) atomicAdd(&deg[ei[E + e]], 1);   // dst = ei[E+e]
}

__global__ void k_bsum(const int* __restrict__ deg, int* __restrict__ bsum, int n) {
    __shared__ int s[256];
    int t = threadIdx.x;
    int i = blockIdx.x * 256 + t;
    s[t] = (i < n) ? deg[i] : 0;
    __syncthreads();
    for (int off = 128; off > 0; off >>= 1) {
        if (t < off) s[t] += s[t + off];
        __syncthreads();
    }
    if (t == 0) bsum[blockIdx.x] = s[0];
}

__global__ void k_bscan(int* __restrict__ bsum, int* __restrict__ tot, int nb) {
    __shared__ int s[1024];
    int t = threadIdx.x;
    int v = (t < nb) ? bsum[t] : 0;
    s[t] = v;
    __syncthreads();
    for (int off = 1; off < 1024; off <<= 1) {
        int u = (t >= off) ? s[t - off] : 0;
        __syncthreads();
        s[t] += u;
        __syncthreads();
    }
    if (t < nb) bsum[t] = s[t] - v;
    if (t == nb - 1) tot[0] = s[t];
}

__global__ void k_rowptr(const int* __restrict__ deg, const int* __restrict__ bsum,
                         int* __restrict__ rowptr, int* __restrict__ cursor,
                         float* __restrict__ dinv, int n) {
    __shared__ int s[256];
    int t = threadIdx.x;
    int i = blockIdx.x * 256 + t;
    int v = (i < n) ? deg[i] : 0;
    s[t] = v;
    __syncthreads();
    for (int off = 1; off < 256; off <<= 1) {
        int u = (t >= off) ? s[t - off] : 0;
        __syncthreads();
        s[t] += u;
        __syncthreads();
    }
    if (i < n) {
        int ex = bsum[blockIdx.x] + s[t] - v;
        rowptr[i] = ex;
        cursor[i] = ex;
        dinv[i] = rsqrtf((float)(v + 1));   // +1 self-loop
    }
}

__global__ void k_fill(const int* __restrict__ ei, int* __restrict__ cursor,
                       const float* __restrict__ dinv, int2* __restrict__ csr, int E) {
    int e = blockIdx.x * blockDim.x + threadIdx.x;
    if (e >= E) return;
    int s = ei[e];
    int d = ei[E + e];
    int pos = atomicAdd(&cursor[d], 1);
    int2 p;
    p.x = s;
    p.y = __float_as_int(dinv[s] * dinv[d]);
    csr[pos] = p;
}

__device__ __forceinline__ ushort_t f2bf_rne(float f) {
    uint_t u = __float_as_uint(f);
    u += 0x7fffu + ((u >> 16) & 1u);
    return (ushort_t)(u >> 16);
}
__device__ __forceinline__ float bf2f(ushort_t h) {
    return __uint_as_float((uint_t)h << 16);
}

// ---- Ybf16[N,128] = X[N,128] @ W[128,128].  BM=64, BK=32; 4x8 microtile.
// Column split {4c, 64+4c} keeps both sW ds_read_b128 at 2-way bank aliasing.
__global__ __launch_bounds__(256) void k_gemm128(const float* __restrict__ X,
                                                 const float* __restrict__ W,
                                                 ushort_t* __restrict__ Y, int N) {
    __shared__ float sX[32][68];
    __shared__ float sW[32][128];
    const int tid = threadIdx.x;
    const int bm = blockIdx.x * 64;
    const int m0 = (tid >> 4) * 4;   // 0..60
    const int c4 = (tid & 15) * 4;   // 0..60
    const int xr = tid >> 3;
    const int xf = tid & 7;
    float acc[4][8] = {};
    for (int k0 = 0; k0 < 128; k0 += 32) {
        #pragma unroll
        for (int rr = 0; rr < 2; ++rr) {
            int row = bm + xr + rr * 32;
            int rc = min(row, N - 1);
            float4 v = *(const float4*)(X + (size_t)rc * 128 + k0 + xf * 4);
            int m = xr + rr * 32;
            sX[xf * 4 + 0][m] = v.x;
            sX[xf * 4 + 1][m] = v.y;
            sX[xf * 4 + 2][m] = v.z;
            sX[xf * 4 + 3][m] = v.w;
        }
        #pragma unroll
        for (int it = 0; it < 4; ++it) {
            int i = tid + it * 256;
            int wr = i >> 5;
            int wf = i & 31;
            *(float4*)(&sW[wr][wf * 4]) =
                *(const float4*)(W + (size_t)(k0 + wr) * 128 + wf * 4);
        }
        __syncthreads();
        #pragma unroll
        for (int kk = 0; kk < 32; ++kk) {
            float4 a  = *(const float4*)(&sX[kk][m0]);
            float4 b0 = *(const float4*)(&sW[kk][c4]);
            float4 b1 = *(const float4*)(&sW[kk][64 + c4]);
            float av[4] = {a.x, a.y, a.z, a.w};
            float bv[8] = {b0.x, b0.y, b0.z, b0.w, b1.x, b1.y, b1.z, b1.w};
            #pragma unroll
            for (int r = 0; r < 4; ++r)
                #pragma unroll
                for (int c = 0; c < 8; ++c)
                    acc[r][c] = fmaf(av[r], bv[c], acc[r][c]);
        }
        __syncthreads();
    }
    #pragma unroll
    for (int r = 0; r < 4; ++r) {
        int row = bm + m0 + r;
        if (row < N) {
            ushort4 o0 = {f2bf_rne(acc[r][0]), f2bf_rne(acc[r][1]),
                          f2bf_rne(acc[r][2]), f2bf_rne(acc[r][3])};
            ushort4 o1 = {f2bf_rne(acc[r][4]), f2bf_rne(acc[r][5]),
                          f2bf_rne(acc[r][6]), f2bf_rne(acc[r][7])};
            *(ushort4*)(Y + (size_t)row * 128 + c4)      = o0;
            *(ushort4*)(Y + (size_t)row * 128 + 64 + c4) = o1;
        }
    }
}

// ---- Y[N,40] = X[N,128] @ W[128,40].  BM=128, BK=32; 4x5 microtile. fp32. --
__global__ __launch_bounds__(256) void k_gemm40(const float* __restrict__ X,
                                                const float* __restrict__ W,
                                                float* __restrict__ Y, int N) {
    __shared__ float sX[32][132];
    __shared__ float sW[32][40];
    const int tid = threadIdx.x;
    const int bm = blockIdx.x * 128;
    const int m0 = (tid >> 3) * 4;
    const int n0 = (tid & 7) * 5;
    const int xf = tid & 7;
    float acc[4][5] = {};
    for (int k0 = 0; k0 < 128; k0 += 32) {
        #pragma unroll
        for (int it = 0; it < 4; ++it) {
            int i = tid + it * 256;
            int row = bm + (i >> 3);
            int rc = min(row, N - 1);
            float4 v = *(const float4*)(X + (size_t)rc * 128 + k0 + xf * 4);
            int m = i >> 3;
            sX[xf * 4 + 0][m] = v.x;
            sX[xf * 4 + 1][m] = v.y;
            sX[xf * 4 + 2][m] = v.z;
            sX[xf * 4 + 3][m] = v.w;
        }
        for (int i = tid; i < 320; i += 256) {
            int wr = i / 10;
            int wf = i - wr * 10;
            *(float4*)(&sW[wr][wf * 4]) =
                *(const float4*)(W + (size_t)(k0 + wr) * 40 + wf * 4);
        }
        __syncthreads();
        #pragma unroll
        for (int kk = 0; kk < 32; ++kk) {
            float4 a = *(const float4*)(&sX[kk][m0]);
            float av[4] = {a.x, a.y, a.z, a.w};
            #pragma unroll
            for (int c = 0; c < 5; ++c) {
                float b = sW[kk][n0 + c];
                #pragma unroll
                for (int r = 0; r < 4; ++r)
                    acc[r][c] = fmaf(av[r], b, acc[r][c]);
            }
        }
        __syncthreads();
    }
    #pragma unroll
    for (int r = 0; r < 4; ++r) {
        int row = bm + m0 + r;
        if (row < N) {
            #pragma unroll
            for (int c = 0; c < 5; ++c)
                Y[(size_t)row * 40 + n0 + c] = acc[r][c];
        }
    }
}

// Half-wave (32 lanes) per dst, F=128 bf16: lane holds 4 cols as ushort4;
// a half-wave gather reads one 256-B row = 2 cache lines.  fp32 accumulate.
// Unroll 8 -> 8 gathers in flight.  csr via nontemporal loads.
template <bool RELU>
__global__ __launch_bounds__(256) void k_agg128(
        const ushort_t* __restrict__ XW, const int* __restrict__ rowptr,
        const long long* __restrict__ csr, const float* __restrict__ dinv,
        const float* __restrict__ bias, float* __restrict__ out, int n) {
    const int lane = threadIdx.x & 31;
    const int sub  = threadIdx.x >> 5;
    const int d = blockIdx.x * 8 + sub;
    if (d >= n) return;
    const ushort4* xw = (const ushort4*)XW;     // row stride 32 ushort4
    float dv = dinv[d];
    float w = dv * dv;
    ushort4 sq = xw[(size_t)d * 32 + lane];
    float4 a;
    a.x = w * bf2f(sq.x); a.y = w * bf2f(sq.y);
    a.z = w * bf2f(sq.z); a.w = w * bf2f(sq.w);
    int j = rowptr[d], end = rowptr[d + 1];
    for (; j + 8 <= end; j += 8) {
        long long l0 = __builtin_nontemporal_load(&csr[j + 0]);
        long long l1 = __builtin_nontemporal_load(&csr[j + 1]);
        long long l2 = __builtin_nontemporal_load(&csr[j + 2]);
        long long l3 = __builtin_nontemporal_load(&csr[j + 3]);
        long long l4 = __builtin_nontemporal_load(&csr[j + 4]);
        long long l5 = __builtin_nontemporal_load(&csr[j + 5]);
        long long l6 = __builtin_nontemporal_load(&csr[j + 6]);
        long long l7 = __builtin_nontemporal_load(&csr[j + 7]);
        ushort4 u0 = xw[(size_t)(int)l0 * 32 + lane];
        ushort4 u1 = xw[(size_t)(int)l1 * 32 + lane];
        ushort4 u2 = xw[(size_t)(int)l2 * 32 + lane];
        ushort4 u3 = xw[(size_t)(int)l3 * 32 + lane];
        ushort4 u4 = xw[(size_t)(int)l4 * 32 + lane];
        ushort4 u5 = xw[(size_t)(int)l5 * 32 + lane];
        ushort4 u6 = xw[(size_t)(int)l6 * 32 + lane];
        ushort4 u7 = xw[(size_t)(int)l7 * 32 + lane];
        float w0 = __int_as_float((int)(l0 >> 32));
        float w1 = __int_as_float((int)(l1 >> 32));
        float w2 = __int_as_float((int)(l2 >> 32));
        float w3 = __int_as_float((int)(l3 >> 32));
        float w4 = __int_as_float((int)(l4 >> 32));
        float w5 = __int_as_float((int)(l5 >> 32));
        float w6 = __int_as_float((int)(l6 >> 32));
        float w7 = __int_as_float((int)(l7 >> 32));
        a.x = fmaf(w0, bf2f(u0.x), a.x); a.y = fmaf(w0, bf2f(u0.y), a.y);
        a.z = fmaf(w0, bf2f(u0.z), a.z); a.w = fmaf(w0, bf2f(u0.w), a.w);
        a.x = fmaf(w1, bf2f(u1.x), a.x); a.y = fmaf(w1, bf2f(u1.y), a.y);
        a.z = fmaf(w1, bf2f(u1.z), a.z); a.w = fmaf(w1, bf2f(u1.w), a.w);
        a.x = fmaf(w2, bf2f(u2.x), a.x); a.y = fmaf(w2, bf2f(u2.y), a.y);
        a.z = fmaf(w2, bf2f(u2.z), a.z); a.w = fmaf(w2, bf2f(u2.w), a.w);
        a.x = fmaf(w3, bf2f(u3.x), a.x); a.y = fmaf(w3, bf2f(u3.y), a.y);
        a.z = fmaf(w3, bf2f(u3.z), a.z); a.w = fmaf(w3, bf2f(u3.w), a.w);
        a.x = fmaf(w4, bf2f(u4.x), a.x); a.y = fmaf(w4, bf2f(u4.y), a.y);
        a.z = fmaf(w4, bf2f(u4.z), a.z); a.w = fmaf(w4, bf2f(u4.w), a.w);
        a.x = fmaf(w5, bf2f(u5.x), a.x); a.y = fmaf(w5, bf2f(u5.y), a.y);
        a.z = fmaf(w5, bf2f(u5.z), a.z); a.w = fmaf(w5, bf2f(u5.w), a.w);
        a.x = fmaf(w6, bf2f(u6.x), a.x); a.y = fmaf(w6, bf2f(u6.y), a.y);
        a.z = fmaf(w6, bf2f(u6.z), a.z); a.w = fmaf(w6, bf2f(u6.w), a.w);
        a.x = fmaf(w7, bf2f(u7.x), a.x); a.y = fmaf(w7, bf2f(u7.y), a.y);
        a.z = fmaf(w7, bf2f(u7.z), a.z); a.w = fmaf(w7, bf2f(u7.w), a.w);
    }
    for (; j < end; ++j) {
        long long l = __builtin_nontemporal_load(&csr[j]);
        float wj = __int_as_float((int)(l >> 32));
        ushort4 u = xw[(size_t)(int)l * 32 + lane];
        a.x = fmaf(wj, bf2f(u.x), a.x); a.y = fmaf(wj, bf2f(u.y), a.y);
        a.z = fmaf(wj, bf2f(u.z), a.z); a.w = fmaf(wj, bf2f(u.w), a.w);
    }
    float4 b = ((const float4*)bias)[lane];
    a.x += b.x; a.y += b.y; a.z += b.z; a.w += b.w;
    if (RELU) {
        a.x = fmaxf(a.x, 0.f); a.y = fmaxf(a.y, 0.f);
        a.z = fmaxf(a.z, 0.f); a.w = fmaxf(a.w, 0.f);
    }
    ((float4*)out)[(size_t)d * 32 + lane] = a;
}

// Half-wave per dst, F=40 fp32: lanes 0..19 hold float2 (2 cols each).
__global__ __launch_bounds__(256) void k_agg40(
        const float* __restrict__ XW, const int* __restrict__ rowptr,
        const long long* __restrict__ csr, const float* __restrict__ dinv,
        const float* __restrict__ bias, float* __restrict__ out, int n) {
    const int lane = threadIdx.x & 31;
    const int sub  = threadIdx.x >> 5;
    const int d = blockIdx.x * 8 + sub;
    if (d >= n || lane >= 20) return;
    const float2* xw2 = (const float2*)XW;      // row stride 20 float2
    float dv = dinv[d];
    float w = dv * dv;
    float2 v = xw2[(size_t)d * 20 + lane];
    float2 a;
    a.x = w * v.x; a.y = w * v.y;
    int j = rowptr[d], end = rowptr[d + 1];
    for (; j + 4 <= end; j += 4) {
        long long l0 = __builtin_nontemporal_load(&csr[j + 0]);
        long long l1 = __builtin_nontemporal_load(&csr[j + 1]);
        long long l2 = __builtin_nontemporal_load(&csr[j + 2]);
        long long l3 = __builtin_nontemporal_load(&csr[j + 3]);
        float2 u0 = xw2[(size_t)(int)l0 * 20 + lane];
        float2 u1 = xw2[(size_t)(int)l1 * 20 + lane];
        float2 u2 = xw2[(size_t)(int)l2 * 20 + lane];
        float2 u3 = xw2[(size_t)(int)l3 * 20 + lane];
        float w0 = __int_as_float((int)(l0 >> 32));
        float w1 = __int_as_float((int)(l1 >> 32));
        float w2 = __int_as_float((int)(l2 >> 32));
        float w3 = __int_as_float((int)(l3 >> 32));
        a.x = fmaf(w0, u0.x, a.x); a.y = fmaf(w0, u0.y, a.y);
        a.x = fmaf(w1, u1.x, a.x); a.y = fmaf(w1, u1.y, a.y);
        a.x = fmaf(w2, u2.x, a.x); a.y = fmaf(w2, u2.y, a.y);
        a.x = fmaf(w3, u3.x, a.x); a.y = fmaf(w3, u3.y, a.y);
    }
    for (; j < end; ++j) {
        long long l = __builtin_nontemporal_load(&csr[j]);
        float wj = __int_as_float((int)(l >> 32));
        float2 u = xw2[(size_t)(int)l * 20 + lane];
        a.x = fmaf(wj, u.x, a.x); a.y = fmaf(wj, u.y, a.y);
    }
    float2 b = ((const float2*)bias)[lane];
    a.x += b.x; a.y += b.y;
    ((float2*)out)[(size_t)d * 20 + lane] = a;
}

static inline int cdiv(long long a, int b) { return (int)((a + b - 1) / b); }

extern "C" void kernel_launch(void* const* d_in, const int* in_sizes, int n_in,
                              void* d_out, int out_size, void* d_ws, size_t ws_size,
                              hipStream_t stream) {
    const float* x  = (const float*)d_in[0];
    const int*   ei = (const int*)d_in[1];
    const float* W1 = (const float*)d_in[2];
    const float* b1 = (const float*)d_in[3];
    const float* W2 = (const float*)d_in[4];
    const float* b2 = (const float*)d_in[5];
    const float* W3 = (const float*)d_in[6];
    const float* b3 = (const float*)d_in[7];
    float* out = (float*)d_out;

    const int N = in_sizes[0] / 128;   // 50000
    const int E = in_sizes[1] / 2;     // 800000

    char* ws = (char*)d_ws;
    int*   deg    = (int*)ws;                 ws += (size_t)N * 4;
    int*   rowptr = (int*)ws;                 ws += (size_t)(N + 1) * 4;
    int*   cursor = (int*)ws;                 ws += (size_t)N * 4;
    float* dinv   = (float*)ws;               ws += (size_t)N * 4;
    int*   bsum   = (int*)ws;                 ws += (size_t)1024 * 4;
    ws = (char*)(((uintptr_t)ws + 15) & ~(uintptr_t)15);
    int2*  csr    = (int2*)ws;                ws += (size_t)E * 8;
    char*  bufA   = ws;                       ws += (size_t)N * 128 * 4;  // bf16 XW (layers 1-2) / f32 XW40 (layer 3)
    float* bufB   = (float*)ws;
    const long long* csr64 = (const long long*)csr;

    const int BT = 256;
    const int nb = cdiv(N, 256);

    // CSR build (per call; no state survives between calls)
    hipMemsetAsync(deg, 0, (size_t)N * 4, stream);
    k_deg_count<<<cdiv(E, BT), BT, 0, stream>>>(ei, deg, E);
    k_bsum<<<nb, 256, 0, stream>>>(deg, bsum, N);
    k_bscan<<<1, 1024, 0, stream>>>(bsum, rowptr + N, nb);
    k_rowptr<<<nb, 256, 0, stream>>>(deg, bsum, rowptr, cursor, dinv, N);
    k_fill<<<cdiv(E, BT), BT, 0, stream>>>(ei, cursor, dinv, csr, E);

    // layer 1
    k_gemm128<<<cdiv(N, 64), 256, 0, stream>>>(x, W1, (ushort_t*)bufA, N);
    k_agg128<true><<<cdiv(N, 8), 256, 0, stream>>>((const ushort_t*)bufA, rowptr, csr64, dinv, b1, bufB, N);
    // layer 2
    k_gemm128<<<cdiv(N, 64), 256, 0, stream>>>(bufB, W2, (ushort_t*)bufA, N);
    k_agg128<true><<<cdiv(N, 8), 256, 0, stream>>>((const ushort_t*)bufA, rowptr, csr64, dinv, b2, bufB, N);
    // layer 3
    k_gemm40<<<cdiv(N, 128), 256, 0, stream>>>(bufB, W3, (float*)bufA, N);
    k_agg40<<<cdiv(N, 8), 256, 0, stream>>>((const float*)bufA, rowptr, csr64, dinv, b3, out, N);
}

// Round 10
// 351.100 us; speedup vs baseline: 2.0055x; 1.0471x over previous
//
#include <hip/hip_runtime.h>

typedef unsigned short ushort_t;
typedef unsigned int uint_t;

// ---------------------------------------------------------------------------
// GCN 3-layer forward.  N=50000, E=800000, D=H=128, C=40.
// Round 10: apply the R9 byte-shrink lever to the layer-3 gather.  agg40's
// fp32 rows were 160 B and line-UNaligned -> ~2.25 cache lines per random
// gather (~230 MB fabric).  Now XW3 is staged bf16 with row stride 64
// elements = one aligned 128-B line -> 1 line/edge (~102 MB payload).
// gemm40 writes the padded bf16 layout; agg40 gathers ushort2 x 20 lanes,
// fp32 accumulate, fp32 output.  agg128 path unchanged from R9.
// ws layout: [deg:N int][rowptr:N+1 int][cursor:N int][dinv:N f32][bsum:1024 int]
//            [csr:E int2 (src, w-bits)][bufA:N*128*4 B][bufB:N*128 f32]
// ---------------------------------------------------------------------------

__global__ void k_deg_count(const int* __restrict__ ei, int* __restrict__ deg, int E) {
    int e = blockIdx.x * blockDim.x + threadIdx.x;
    if (e < E) atomicAdd(&deg[ei[E + e]], 1);   // dst = ei[E+e]
}

__global__ void k_bsum(const int* __restrict__ deg, int* __restrict__ bsum, int n) {
    __shared__ int s[256];
    int t = threadIdx.x;
    int i = blockIdx.x * 256 + t;
    s[t] = (i < n) ? deg[i] : 0;
    __syncthreads();
    for (int off = 128; off > 0; off >>= 1) {
        if (t < off) s[t] += s[t + off];
        __syncthreads();
    }
    if (t == 0) bsum[blockIdx.x] = s[0];
}

__global__ void k_bscan(int* __restrict__ bsum, int* __restrict__ tot, int nb) {
    __shared__ int s[1024];
    int t = threadIdx.x;
    int v = (t < nb) ? bsum[t] : 0;
    s[t] = v;
    __syncthreads();
    for (int off = 1; off < 1024; off <<= 1) {
        int u = (t >= off) ? s[t - off] : 0;
        __syncthreads();
        s[t] += u;
        __syncthreads();
    }
    if (t < nb) bsum[t] = s[t] - v;
    if (t == nb - 1) tot[0] = s[t];
}

__global__ void k_rowptr(const int* __restrict__ deg, const int* __restrict__ bsum,
                         int* __restrict__ rowptr, int* __restrict__ cursor,
                         float* __restrict__ dinv, int n) {
    __shared__ int s[256];
    int t = threadIdx.x;
    int i = blockIdx.x * 256 + t;
    int v = (i < n) ? deg[i] : 0;
    s[t] = v;
    __syncthreads();
    for (int off = 1; off < 256; off <<= 1) {
        int u = (t >= off) ? s[t - off] : 0;
        __syncthreads();
        s[t] += u;
        __syncthreads();
    }
    if (i < n) {
        int ex = bsum[blockIdx.x] + s[t] - v;
        rowptr[i] = ex;
        cursor[i] = ex;
        dinv[i] = rsqrtf((float)(v + 1));   // +1 self-loop
    }
}

__global__ void k_fill(const int* __restrict__ ei, int* __restrict__ cursor,
                       const float* __restrict__ dinv, int2* __restrict__ csr, int E) {
    int e = blockIdx.x * blockDim.x + threadIdx.x;
    if (e >= E) return;
    int s = ei[e];
    int d = ei[E + e];
    int pos = atomicAdd(&cursor[d], 1);
    int2 p;
    p.x = s;
    p.y = __float_as_int(dinv[s] * dinv[d]);
    csr[pos] = p;
}

__device__ __forceinline__ ushort_t f2bf_rne(float f) {
    uint_t u = __float_as_uint(f);
    u += 0x7fffu + ((u >> 16) & 1u);
    return (ushort_t)(u >> 16);
}
__device__ __forceinline__ float bf2f(ushort_t h) {
    return __uint_as_float((uint_t)h << 16);
}

// ---- Ybf16[N,128] = X[N,128] @ W[128,128].  BM=64, BK=32; 4x8 microtile.
__global__ __launch_bounds__(256) void k_gemm128(const float* __restrict__ X,
                                                 const float* __restrict__ W,
                                                 ushort_t* __restrict__ Y, int N) {
    __shared__ float sX[32][68];
    __shared__ float sW[32][128];
    const int tid = threadIdx.x;
    const int bm = blockIdx.x * 64;
    const int m0 = (tid >> 4) * 4;   // 0..60
    const int c4 = (tid & 15) * 4;   // 0..60
    const int xr = tid >> 3;
    const int xf = tid & 7;
    float acc[4][8] = {};
    for (int k0 = 0; k0 < 128; k0 += 32) {
        #pragma unroll
        for (int rr = 0; rr < 2; ++rr) {
            int row = bm + xr + rr * 32;
            int rc = min(row, N - 1);
            float4 v = *(const float4*)(X + (size_t)rc * 128 + k0 + xf * 4);
            int m = xr + rr * 32;
            sX[xf * 4 + 0][m] = v.x;
            sX[xf * 4 + 1][m] = v.y;
            sX[xf * 4 + 2][m] = v.z;
            sX[xf * 4 + 3][m] = v.w;
        }
        #pragma unroll
        for (int it = 0; it < 4; ++it) {
            int i = tid + it * 256;
            int wr = i >> 5;
            int wf = i & 31;
            *(float4*)(&sW[wr][wf * 4]) =
                *(const float4*)(W + (size_t)(k0 + wr) * 128 + wf * 4);
        }
        __syncthreads();
        #pragma unroll
        for (int kk = 0; kk < 32; ++kk) {
            float4 a  = *(const float4*)(&sX[kk][m0]);
            float4 b0 = *(const float4*)(&sW[kk][c4]);
            float4 b1 = *(const float4*)(&sW[kk][64 + c4]);
            float av[4] = {a.x, a.y, a.z, a.w};
            float bv[8] = {b0.x, b0.y, b0.z, b0.w, b1.x, b1.y, b1.z, b1.w};
            #pragma unroll
            for (int r = 0; r < 4; ++r)
                #pragma unroll
                for (int c = 0; c < 8; ++c)
                    acc[r][c] = fmaf(av[r], bv[c], acc[r][c]);
        }
        __syncthreads();
    }
    #pragma unroll
    for (int r = 0; r < 4; ++r) {
        int row = bm + m0 + r;
        if (row < N) {
            ushort4 o0 = {f2bf_rne(acc[r][0]), f2bf_rne(acc[r][1]),
                          f2bf_rne(acc[r][2]), f2bf_rne(acc[r][3])};
            ushort4 o1 = {f2bf_rne(acc[r][4]), f2bf_rne(acc[r][5]),
                          f2bf_rne(acc[r][6]), f2bf_rne(acc[r][7])};
            *(ushort4*)(Y + (size_t)row * 128 + c4)      = o0;
            *(ushort4*)(Y + (size_t)row * 128 + 64 + c4) = o1;
        }
    }
}

// ---- Ybf16[N,40 (stride 64)] = X[N,128] @ W[128,40].  BM=128, BK=32. ----
// Row stride 64 bf16 = 128 B: each row is exactly one aligned cache line.
__global__ __launch_bounds__(256) void k_gemm40(const float* __restrict__ X,
                                                const float* __restrict__ W,
                                                ushort_t* __restrict__ Y, int N) {
    __shared__ float sX[32][132];
    __shared__ float sW[32][40];
    const int tid = threadIdx.x;
    const int bm = blockIdx.x * 128;
    const int m0 = (tid >> 3) * 4;
    const int n0 = (tid & 7) * 5;
    const int xf = tid & 7;
    float acc[4][5] = {};
    for (int k0 = 0; k0 < 128; k0 += 32) {
        #pragma unroll
        for (int it = 0; it < 4; ++it) {
            int i = tid + it * 256;
            int row = bm + (i >> 3);
            int rc = min(row, N - 1);
            float4 v = *(const float4*)(X + (size_t)rc * 128 + k0 + xf * 4);
            int m = i >> 3;
            sX[xf * 4 + 0][m] = v.x;
            sX[xf * 4 + 1][m] = v.y;
            sX[xf * 4 + 2][m] = v.z;
            sX[xf * 4 + 3][m] = v.w;
        }
        for (int i = tid; i < 320; i += 256) {
            int wr = i / 10;
            int wf = i - wr * 10;
            *(float4*)(&sW[wr][wf * 4]) =
                *(const float4*)(W + (size_t)(k0 + wr) * 40 + wf * 4);
        }
        __syncthreads();
        #pragma unroll
        for (int kk = 0; kk < 32; ++kk) {
            float4 a = *(const float4*)(&sX[kk][m0]);
            float av[4] = {a.x, a.y, a.z, a.w};
            #pragma unroll
            for (int c = 0; c < 5; ++c) {
                float b = sW[kk][n0 + c];
                #pragma unroll
                for (int r = 0; r < 4; ++r)
                    acc[r][c] = fmaf(av[r], b, acc[r][c]);
            }
        }
        __syncthreads();
    }
    #pragma unroll
    for (int r = 0; r < 4; ++r) {
        int row = bm + m0 + r;
        if (row < N) {
            #pragma unroll
            for (int c = 0; c < 5; ++c)
                Y[(size_t)row * 64 + n0 + c] = f2bf_rne(acc[r][c]);
        }
    }
}

// Half-wave (32 lanes) per dst, F=128 bf16: lane holds 4 cols as ushort4;
// a half-wave gather reads one 256-B row = 2 cache lines.  fp32 accumulate.
template <bool RELU>
__global__ __launch_bounds__(256) void k_agg128(
        const ushort_t* __restrict__ XW, const int* __restrict__ rowptr,
        const long long* __restrict__ csr, const float* __restrict__ dinv,
        const float* __restrict__ bias, float* __restrict__ out, int n) {
    const int lane = threadIdx.x & 31;
    const int sub  = threadIdx.x >> 5;
    const int d = blockIdx.x * 8 + sub;
    if (d >= n) return;
    const ushort4* xw = (const ushort4*)XW;     // row stride 32 ushort4
    float dv = dinv[d];
    float w = dv * dv;
    ushort4 sq = xw[(size_t)d * 32 + lane];
    float4 a;
    a.x = w * bf2f(sq.x); a.y = w * bf2f(sq.y);
    a.z = w * bf2f(sq.z); a.w = w * bf2f(sq.w);
    int j = rowptr[d], end = rowptr[d + 1];
    for (; j + 8 <= end; j += 8) {
        long long l0 = __builtin_nontemporal_load(&csr[j + 0]);
        long long l1 = __builtin_nontemporal_load(&csr[j + 1]);
        long long l2 = __builtin_nontemporal_load(&csr[j + 2]);
        long long l3 = __builtin_nontemporal_load(&csr[j + 3]);
        long long l4 = __builtin_nontemporal_load(&csr[j + 4]);
        long long l5 = __builtin_nontemporal_load(&csr[j + 5]);
        long long l6 = __builtin_nontemporal_load(&csr[j + 6]);
        long long l7 = __builtin_nontemporal_load(&csr[j + 7]);
        ushort4 u0 = xw[(size_t)(int)l0 * 32 + lane];
        ushort4 u1 = xw[(size_t)(int)l1 * 32 + lane];
        ushort4 u2 = xw[(size_t)(int)l2 * 32 + lane];
        ushort4 u3 = xw[(size_t)(int)l3 * 32 + lane];
        ushort4 u4 = xw[(size_t)(int)l4 * 32 + lane];
        ushort4 u5 = xw[(size_t)(int)l5 * 32 + lane];
        ushort4 u6 = xw[(size_t)(int)l6 * 32 + lane];
        ushort4 u7 = xw[(size_t)(int)l7 * 32 + lane];
        float w0 = __int_as_float((int)(l0 >> 32));
        float w1 = __int_as_float((int)(l1 >> 32));
        float w2 = __int_as_float((int)(l2 >> 32));
        float w3 = __int_as_float((int)(l3 >> 32));
        float w4 = __int_as_float((int)(l4 >> 32));
        float w5 = __int_as_float((int)(l5 >> 32));
        float w6 = __int_as_float((int)(l6 >> 32));
        float w7 = __int_as_float((int)(l7 >> 32));
        a.x = fmaf(w0, bf2f(u0.x), a.x); a.y = fmaf(w0, bf2f(u0.y), a.y);
        a.z = fmaf(w0, bf2f(u0.z), a.z); a.w = fmaf(w0, bf2f(u0.w), a.w);
        a.x = fmaf(w1, bf2f(u1.x), a.x); a.y = fmaf(w1, bf2f(u1.y), a.y);
        a.z = fmaf(w1, bf2f(u1.z), a.z); a.w = fmaf(w1, bf2f(u1.w), a.w);
        a.x = fmaf(w2, bf2f(u2.x), a.x); a.y = fmaf(w2, bf2f(u2.y), a.y);
        a.z = fmaf(w2, bf2f(u2.z), a.z); a.w = fmaf(w2, bf2f(u2.w), a.w);
        a.x = fmaf(w3, bf2f(u3.x), a.x); a.y = fmaf(w3, bf2f(u3.y), a.y);
        a.z = fmaf(w3, bf2f(u3.z), a.z); a.w = fmaf(w3, bf2f(u3.w), a.w);
        a.x = fmaf(w4, bf2f(u4.x), a.x); a.y = fmaf(w4, bf2f(u4.y), a.y);
        a.z = fmaf(w4, bf2f(u4.z), a.z); a.w = fmaf(w4, bf2f(u4.w), a.w);
        a.x = fmaf(w5, bf2f(u5.x), a.x); a.y = fmaf(w5, bf2f(u5.y), a.y);
        a.z = fmaf(w5, bf2f(u5.z), a.z); a.w = fmaf(w5, bf2f(u5.w), a.w);
        a.x = fmaf(w6, bf2f(u6.x), a.x); a.y = fmaf(w6, bf2f(u6.y), a.y);
        a.z = fmaf(w6, bf2f(u6.z), a.z); a.w = fmaf(w6, bf2f(u6.w), a.w);
        a.x = fmaf(w7, bf2f(u7.x), a.x); a.y = fmaf(w7, bf2f(u7.y), a.y);
        a.z = fmaf(w7, bf2f(u7.z), a.z); a.w = fmaf(w7, bf2f(u7.w), a.w);
    }
    for (; j < end; ++j) {
        long long l = __builtin_nontemporal_load(&csr[j]);
        float wj = __int_as_float((int)(l >> 32));
        ushort4 u = xw[(size_t)(int)l * 32 + lane];
        a.x = fmaf(wj, bf2f(u.x), a.x); a.y = fmaf(wj, bf2f(u.y), a.y);
        a.z = fmaf(wj, bf2f(u.z), a.z); a.w = fmaf(wj, bf2f(u.w), a.w);
    }
    float4 b = ((const float4*)bias)[lane];
    a.x += b.x; a.y += b.y; a.z += b.z; a.w += b.w;
    if (RELU) {
        a.x = fmaxf(a.x, 0.f); a.y = fmaxf(a.y, 0.f);
        a.z = fmaxf(a.z, 0.f); a.w = fmaxf(a.w, 0.f);
    }
    ((float4*)out)[(size_t)d * 32 + lane] = a;
}

// Half-wave per dst, F=40 bf16 rows padded to stride 64 (one 128-B line):
// lanes 0..19 hold ushort2 (2 cols each); fp32 accumulate; fp32 output.
__global__ __launch_bounds__(256) void k_agg40(
        const ushort_t* __restrict__ XW, const int* __restrict__ rowptr,
        const long long* __restrict__ csr, const float* __restrict__ dinv,
        const float* __restrict__ bias, float* __restrict__ out, int n) {
    const int lane = threadIdx.x & 31;
    const int sub  = threadIdx.x >> 5;
    const int d = blockIdx.x * 8 + sub;
    if (d >= n || lane >= 20) return;
    const ushort2* xw = (const ushort2*)XW;     // row stride 32 ushort2
    float dv = dinv[d];
    float w = dv * dv;
    ushort2 sq = xw[(size_t)d * 32 + lane];
    float2 a;
    a.x = w * bf2f(sq.x); a.y = w * bf2f(sq.y);
    int j = rowptr[d], end = rowptr[d + 1];
    for (; j + 4 <= end; j += 4) {
        long long l0 = __builtin_nontemporal_load(&csr[j + 0]);
        long long l1 = __builtin_nontemporal_load(&csr[j + 1]);
        long long l2 = __builtin_nontemporal_load(&csr[j + 2]);
        long long l3 = __builtin_nontemporal_load(&csr[j + 3]);
        ushort2 u0 = xw[(size_t)(int)l0 * 32 + lane];
        ushort2 u1 = xw[(size_t)(int)l1 * 32 + lane];
        ushort2 u2 = xw[(size_t)(int)l2 * 32 + lane];
        ushort2 u3 = xw[(size_t)(int)l3 * 32 + lane];
        float w0 = __int_as_float((int)(l0 >> 32));
        float w1 = __int_as_float((int)(l1 >> 32));
        float w2 = __int_as_float((int)(l2 >> 32));
        float w3 = __int_as_float((int)(l3 >> 32));
        a.x = fmaf(w0, bf2f(u0.x), a.x); a.y = fmaf(w0, bf2f(u0.y), a.y);
        a.x = fmaf(w1, bf2f(u1.x), a.x); a.y = fmaf(w1, bf2f(u1.y), a.y);
        a.x = fmaf(w2, bf2f(u2.x), a.x); a.y = fmaf(w2, bf2f(u2.y), a.y);
        a.x = fmaf(w3, bf2f(u3.x), a.x); a.y = fmaf(w3, bf2f(u3.y), a.y);
    }
    for (; j < end; ++j) {
        long long l = __builtin_nontemporal_load(&csr[j]);
        float wj = __int_as_float((int)(l >> 32));
        ushort2 u = xw[(size_t)(int)l * 32 + lane];
        a.x = fmaf(wj, bf2f(u.x), a.x); a.y = fmaf(wj, bf2f(u.y), a.y);
    }
    float2 b = ((const float2*)bias)[lane];
    a.x += b.x; a.y += b.y;
    ((float2*)out)[(size_t)d * 20 + lane] = a;
}

static inline int cdiv(long long a, int b) { return (int)((a + b - 1) / b); }

extern "C" void kernel_launch(void* const* d_in, const int* in_sizes, int n_in,
                              void* d_out, int out_size, void* d_ws, size_t ws_size,
                              hipStream_t stream) {
    const float* x  = (const float*)d_in[0];
    const int*   ei = (const int*)d_in[1];
    const float* W1 = (const float*)d_in[2];
    const float* b1 = (const float*)d_in[3];
    const float* W2 = (const float*)d_in[4];
    const float* b2 = (const float*)d_in[5];
    const float* W3 = (const float*)d_in[6];
    const float* b3 = (const float*)d_in[7];
    float* out = (float*)d_out;

    const int N = in_sizes[0] / 128;   // 50000
    const int E = in_sizes[1] / 2;     // 800000

    char* ws = (char*)d_ws;
    int*   deg    = (int*)ws;                 ws += (size_t)N * 4;
    int*   rowptr = (int*)ws;                 ws += (size_t)(N + 1) * 4;
    int*   cursor = (int*)ws;                 ws += (size_t)N * 4;
    float* dinv   = (float*)ws;               ws += (size_t)N * 4;
    int*   bsum   = (int*)ws;                 ws += (size_t)1024 * 4;
    ws = (char*)(((uintptr_t)ws + 127) & ~(uintptr_t)127);
    int2*  csr    = (int2*)ws;                ws += (size_t)E * 8;
    char*  bufA   = ws;                       ws += (size_t)N * 128 * 4;  // bf16 XW / bf16 XW40 (stride 64)
    float* bufB   = (float*)ws;
    const long long* csr64 = (const long long*)csr;

    const int BT = 256;
    const int nb = cdiv(N, 256);

    // CSR build (per call; no state survives between calls)
    hipMemsetAsync(deg, 0, (size_t)N * 4, stream);
    k_deg_count<<<cdiv(E, BT), BT, 0, stream>>>(ei, deg, E);
    k_bsum<<<nb, 256, 0, stream>>>(deg, bsum, N);
    k_bscan<<<1, 1024, 0, stream>>>(bsum, rowptr + N, nb);
    k_rowptr<<<nb, 256, 0, stream>>>(deg, bsum, rowptr, cursor, dinv, N);
    k_fill<<<cdiv(E, BT), BT, 0, stream>>>(ei, cursor, dinv, csr, E);

    // layer 1
    k_gemm128<<<cdiv(N, 64), 256, 0, stream>>>(x, W1, (ushort_t*)bufA, N);
    k_agg128<true><<<cdiv(N, 8), 256, 0, stream>>>((const ushort_t*)bufA, rowptr, csr64, dinv, b1, bufB, N);
    // layer 2
    k_gemm128<<<cdiv(N, 64), 256, 0, stream>>>(bufB, W2, (ushort_t*)bufA, N);
    k_agg128<true><<<cdiv(N, 8), 256, 0, stream>>>((const ushort_t*)bufA, rowptr, csr64, dinv, b2, bufB, N);
    // layer 3 (bf16 staged, rows padded to one 128-B line)
    k_gemm40<<<cdiv(N, 128), 256, 0, stream>>>(bufB, W3, (ushort_t*)bufA, N);
    k_agg40<<<cdiv(N, 8), 256, 0, stream>>>((const ushort_t*)bufA, rowptr, csr64, dinv, b3, out, N);
}